// Round 11
// baseline (147.691 us; speedup 1.0000x reference)
//
#include <hip/hip_runtime.h>
#include <hip/hip_bf16.h>

// Decoder loss: keep-mask (kth-value threshold + local max), BCE coord loss,
// bidirectional NN recolor + L1 rgb loss.
// L=16384 candidates, N=10000 targets, K=8 (collapses to argmin; R1-proven).
// R11: barrier-free transposed scan. Rules learned on this part:
//   - grid.sync ~40us (R4); mass __threadfence ~0.4ms (R7); spin-fusion
//     neutral (R9). Kernel boundary ~5us is the cheap sync.
//   - Broadcast LDS scan: ds_read-bound ~42us (R8). Transposed LDS scan:
//     barrier-drain stalls ~45% (R10). Fix: per-lane coalesced global
//     streams from L2 (NOT R5's wave-uniform loads), zero barriers.
//   - Manual multi-chain ILP on one accumulator hurt (R9); 8 independent
//     query-chains per wave is the ILP source here.

typedef unsigned long long ull;

// ---- Kernel 1: init + monotone keys + per-8 local max ----------------------
__global__ __launch_bounds__(256) void k_prep(
    const float* __restrict__ pred, const float* __restrict__ txyz,
    float4* __restrict__ ttile, float4* __restrict__ numden,
    int* __restrict__ zerohit, unsigned int* __restrict__ key,
    unsigned char* __restrict__ islm, int* __restrict__ counters,
    float* __restrict__ out, int L, int N) {
  int gidx = blockIdx.x * 256 + threadIdx.x;
  int gsz = (int)gridDim.x * 256;
  for (int i = gidx; i < N; i += gsz) {
    float x = txyz[3*i], y = txyz[3*i+1], z = txyz[3*i+2];
    ttile[i] = make_float4(x, y, z, fmaf(x, x, fmaf(y, y, z * z)));
  }
  for (int i = gidx; i < L; i += gsz) {
    numden[i] = make_float4(0.f, 0.f, 0.f, 0.f);
    zerohit[i] = 0;
  }
  if (gidx < 8) counters[gidx] = 0;
  if (gidx < 2) out[gidx] = 0.f;
  int ngroups = L >> 3;
  for (int g = gidx; g < ngroups; g += gsz) {
    const float4* pv = (const float4*)pred + (size_t)g * 2;
    float4 a = pv[0], b = pv[1];
    float v[8] = {a.x, a.y, a.z, a.w, b.x, b.y, b.z, b.w};
    int bi = 0; float bv = v[0];
    #pragma unroll
    for (int j = 1; j < 8; ++j) if (v[j] > bv) { bv = v[j]; bi = j; }
    unsigned int kk[8];
    ull lmpack = 0ull;
    #pragma unroll
    for (int j = 0; j < 8; ++j) {
      unsigned int fb = __float_as_uint(v[j]);
      unsigned int mk = (fb & 0x80000000u) ? ~fb : (fb | 0x80000000u);
      if (j == bi) { mk = 0xFF800000u; lmpack |= 1ull << (8 * j); }  // +inf
      kk[j] = mk;
    }
    ((uint4*)key)[g*2]   = make_uint4(kk[0], kk[1], kk[2], kk[3]);
    ((uint4*)key)[g*2+1] = make_uint4(kk[4], kk[5], kk[6], kk[7]);
    *(ull*)(islm + (size_t)g * 8) = lmpack;
  }
}

// ---- helper: pick bin containing rank from LDS hist (wave 0) ---------------
__device__ __forceinline__ void select_bin(
    unsigned int* hist, int nb, unsigned int rank,
    unsigned int* sB, unsigned int* sR, int tid) {
  if (tid < 64) {
    int g = nb >> 6;
    unsigned int sum = 0;
    for (int j = 0; j < g; ++j) sum += hist[tid * g + j];
    unsigned int incl = sum;
    for (int o = 1; o < 64; o <<= 1) {
      unsigned int v = __shfl_up(incl, o);
      if (tid >= o) incl += v;
    }
    unsigned int excl = incl - sum;
    bool cond = (rank >= excl) && (rank < incl);
    unsigned long long bal = __ballot(cond);
    int first = __ffsll((long long)bal) - 1;
    if (tid == first) {
      unsigned int r = rank - excl, cum = 0;
      for (int j = 0; j < g; ++j) {
        unsigned int c = hist[tid * g + j];
        if (r < cum + c) { *sB = (unsigned int)(tid * g + j); *sR = r - cum; break; }
        cum += c;
      }
    }
  }
}

// ---- Kernel 2: exact rank select, self-contained (1 block, 3 sweeps) -------
__global__ __launch_bounds__(256) void k_sel(
    const unsigned int* __restrict__ key, const int* __restrict__ pnum_p,
    float* __restrict__ thr_out, int L) {
  __shared__ unsigned int hist[2048];
  __shared__ unsigned int sB, sR;
  int tid = threadIdx.x;
  unsigned int rank = (unsigned int)(L - pnum_p[0] - 1);
  const uint4* k4 = (const uint4*)key;
  int n4 = L >> 2;
  for (int b = tid; b < 2048; b += 256) hist[b] = 0u;
  __syncthreads();
  for (int i = tid; i < n4; i += 256) {
    uint4 v = k4[i];
    atomicAdd(&hist[v.x >> 21], 1u); atomicAdd(&hist[v.y >> 21], 1u);
    atomicAdd(&hist[v.z >> 21], 1u); atomicAdd(&hist[v.w >> 21], 1u);
  }
  __syncthreads();
  select_bin(hist, 2048, rank, &sB, &sR, tid);
  __syncthreads();
  unsigned int B1 = sB, R1 = sR;
  for (int b = tid; b < 2048; b += 256) hist[b] = 0u;
  __syncthreads();
  for (int i = tid; i < n4; i += 256) {
    uint4 v = k4[i];
    if ((v.x >> 21) == B1) atomicAdd(&hist[(v.x >> 10) & 2047u], 1u);
    if ((v.y >> 21) == B1) atomicAdd(&hist[(v.y >> 10) & 2047u], 1u);
    if ((v.z >> 21) == B1) atomicAdd(&hist[(v.z >> 10) & 2047u], 1u);
    if ((v.w >> 21) == B1) atomicAdd(&hist[(v.w >> 10) & 2047u], 1u);
  }
  __syncthreads();
  select_bin(hist, 2048, R1, &sB, &sR, tid);
  __syncthreads();
  unsigned int B2 = sB, R2 = sR;
  for (int b = tid; b < 1024; b += 256) hist[b] = 0u;
  __syncthreads();
  unsigned int top22 = (B1 << 11) | B2;
  for (int i = tid; i < n4; i += 256) {
    uint4 v = k4[i];
    if ((v.x >> 10) == top22) atomicAdd(&hist[v.x & 1023u], 1u);
    if ((v.y >> 10) == top22) atomicAdd(&hist[v.y & 1023u], 1u);
    if ((v.z >> 10) == top22) atomicAdd(&hist[v.z & 1023u], 1u);
    if ((v.w >> 10) == top22) atomicAdd(&hist[v.w & 1023u], 1u);
  }
  __syncthreads();
  select_bin(hist, 1024, R2, &sB, &sR, tid);
  __syncthreads();
  if (tid == 0) {
    unsigned int fkey = (B1 << 21) | (B2 << 10) | sB;
    unsigned int fb = (fkey & 0x80000000u) ? (fkey & 0x7FFFFFFFu) : ~fkey;
    thr_out[0] = __uint_as_float(fb);
  }
}

// ---- Kernel 3: keep mask + compaction + BCE reduce -------------------------
__global__ __launch_bounds__(256) void k_keepc(
    const float* __restrict__ pred, const unsigned char* __restrict__ islm,
    const float* __restrict__ thr_p, const float* __restrict__ cxyz,
    const int* __restrict__ ktgt, int* __restrict__ keep,
    float4* __restrict__ klist, int* __restrict__ kidx,
    int* __restrict__ counters, float* __restrict__ out, int L) {
  int i = blockIdx.x * 256 + threadIdx.x;
  float thr = thr_p[0];
  float term = 0.f;
  if (i < L) {
    float p = pred[i];
    bool kp = (p > thr) || islm[i];
    keep[i] = kp ? 1 : 0;
    if (kp) {
      int pos = atomicAdd(&counters[0], 1);   // order irrelevant (no ties)
      float x = cxyz[3*i], y = cxyz[3*i+1], z = cxyz[3*i+2];
      klist[pos] = make_float4(x, y, z, fmaf(x, x, fmaf(y, y, z * z)));
      kidx[pos] = i;
    }
    float t = (float)ktgt[i];
    term = fmaxf(p, 0.f) - p * t + log1pf(expf(-fabsf(p)));
  }
  for (int o = 32; o > 0; o >>= 1) term += __shfl_down(term, o);
  if ((threadIdx.x & 63) == 0) atomicAdd(&out[0], term);
}

// ---- Kernel 4: barrier-free transposed dual-role scan ----------------------
// Wave owns 8 queries; lanes stream the L2-resident list with coalesced
// per-lane float4 loads (stride 64). No LDS, no barriers, no atomics.
__global__ __launch_bounds__(256) void k_scanw(
    const float* __restrict__ txyz, const float4* __restrict__ klist,
    const int* __restrict__ kidx, const float4* __restrict__ ttile,
    const int* __restrict__ counters, ull* __restrict__ tmin,
    int* __restrict__ fidx, int L, int N, int NBW) {
  int tid = threadIdx.x;
  int lane = tid & 63;
  int wv = tid >> 6;
  int kc = counters[0];
  int bid = blockIdx.x;

  const float4* list; int listn; int q0;
  float qx[8], qy[8], qz[8];
  if (bid < NBW) {           // backward: queries = targets, list = klist
    q0 = (bid * 4 + wv) * 8;
    #pragma unroll
    for (int j = 0; j < 8; ++j) {
      int a = min(q0 + j, N - 1);
      qx[j] = txyz[3*a]; qy[j] = txyz[3*a+1]; qz[j] = txyz[3*a+2];
    }
    list = klist; listn = kc;
  } else {                   // forward: queries = kept candidates, list = ttile
    int eb = (bid - NBW) * 32;
    if (eb >= kc) return;    // uniform early-exit
    q0 = eb + wv * 8;
    #pragma unroll
    for (int j = 0; j < 8; ++j) {
      int a = min(q0 + j, kc - 1);
      float4 A = klist[a];
      qx[j] = A.x; qy[j] = A.y; qz[j] = A.z;
    }
    list = ttile; listn = N;
  }
  float nx[8], ny[8], nz[8], bb[8]; int ii[8];
  #pragma unroll
  for (int j = 0; j < 8; ++j) {
    nx[j] = -2.f * qx[j]; ny[j] = -2.f * qy[j]; nz[j] = -2.f * qz[j];
    bb[j] = 3e38f; ii[j] = 0;
  }

  int i = lane;
  for (; i + 64 < listn; i += 128) {     // 2 loads in flight
    float4 A = list[i];
    float4 B = list[i + 64];
    #pragma unroll
    for (int j = 0; j < 8; ++j) {
      // monotone surrogate |p|^2 - 2 q.p (argmin-equiv to |q-p|^2)
      float dA = fmaf(nx[j], A.x, A.w);
      dA = fmaf(ny[j], A.y, dA);
      dA = fmaf(nz[j], A.z, dA);
      if (dA < bb[j]) { bb[j] = dA; ii[j] = i; }
      float dB = fmaf(nx[j], B.x, B.w);
      dB = fmaf(ny[j], B.y, dB);
      dB = fmaf(nz[j], B.z, dB);
      if (dB < bb[j]) { bb[j] = dB; ii[j] = i + 64; }
    }
  }
  if (i < listn) {
    float4 A = list[i];
    #pragma unroll
    for (int j = 0; j < 8; ++j) {
      float dA = fmaf(nx[j], A.x, A.w);
      dA = fmaf(ny[j], A.y, dA);
      dA = fmaf(nz[j], A.z, dA);
      if (dA < bb[j]) { bb[j] = dA; ii[j] = i; }
    }
  }

  // wave argmin reduce (prefer lower index on exact tie, matching jnp)
  #pragma unroll
  for (int o = 32; o > 0; o >>= 1) {
    #pragma unroll
    for (int j = 0; j < 8; ++j) {
      float ob = __shfl_xor(bb[j], o);
      int   oi = __shfl_xor(ii[j], o);
      if (ob < bb[j] || (ob == bb[j] && oi < ii[j])) { bb[j] = ob; ii[j] = oi; }
    }
  }
  if (lane == 0) {
    if (bid < NBW) {
      #pragma unroll
      for (int j = 0; j < 8; ++j) {
        int t = q0 + j;
        if (t < N) {
          float4 cd = klist[ii[j]];
          float dx = txyz[3*t] - cd.x, dy = txyz[3*t+1] - cd.y, dz = txyz[3*t+2] - cd.z;
          float dtrue = fmaf(dx, dx, fmaf(dy, dy, dz * dz));  // exact (R1-proven)
          tmin[t] = ((ull)__float_as_uint(dtrue) << 32) | (unsigned int)kidx[ii[j]];
        }
      }
    } else {
      #pragma unroll
      for (int j = 0; j < 8; ++j) {
        int e = q0 + j;
        if (e < kc) fidx[kidx[e]] = ii[j];
      }
    }
  }
}

// ---- Kernel 5: scatter weighted colors into num/den ------------------------
__global__ __launch_bounds__(256) void k_scatter(
    const float* __restrict__ trgb, const ull* __restrict__ tmin,
    float4* __restrict__ numden, int* __restrict__ zerohit,
    float4* __restrict__ zcolor, int N) {
  int t = blockIdx.x * 256 + threadIdx.x;
  if (t >= N) return;
  ull pack = tmin[t];
  float d = __uint_as_float((unsigned int)(pack >> 32));
  int idx = (int)(pack & 0xFFFFFFFFull);
  float r = trgb[3*t], g = trgb[3*t+1], b = trgb[3*t+2];
  if (d == 0.0f) {
    zerohit[idx] = 1;
    zcolor[idx] = make_float4(r, g, b, 0.f);
  } else {
    float w = 1.0f / sqrtf(fmaxf(d, 1e-30f));
    atomicAdd(&numden[idx].x, r * w);
    atomicAdd(&numden[idx].y, g * w);
    atomicAdd(&numden[idx].z, b * w);
    atomicAdd(&numden[idx].w, w);
  }
}

// ---- Kernel 6: final recolor select + L1 reduce ----------------------------
__global__ __launch_bounds__(256) void k_loss(
    const float* __restrict__ crgb, const float* __restrict__ trgb,
    const int* __restrict__ keep, const float4* __restrict__ numden,
    const int* __restrict__ zerohit, const float4* __restrict__ zcolor,
    const int* __restrict__ fidx, float* __restrict__ out, int L) {
  int l = blockIdx.x * 256 + threadIdx.x;
  float loss = 0.f;
  if (l < L && keep[l]) {
    float rr, rg, rb;
    if (zerohit[l]) {
      float4 z = zcolor[l]; rr = z.x; rg = z.y; rb = z.z;
    } else {
      float4 nd = numden[l];
      if (nd.w != 0.f) { rr = nd.x / nd.w; rg = nd.y / nd.w; rb = nd.z / nd.w; }
      else {
        int ti = fidx[l];
        rr = trgb[3*ti]; rg = trgb[3*ti+1]; rb = trgb[3*ti+2];
      }
    }
    float sr = crgb[3*l]*255.f, sg = crgb[3*l+1]*255.f, sb = crgb[3*l+2]*255.f;
    loss = fabsf(sr - rr) + fabsf(sg - rg) + fabsf(sb - rb);
  }
  for (int o = 32; o > 0; o >>= 1) loss += __shfl_down(loss, o);
  if ((threadIdx.x & 63) == 0) atomicAdd(&out[1], loss);
}

extern "C" void kernel_launch(void* const* d_in, const int* in_sizes, int n_in,
                              void* d_out, int out_size, void* d_ws, size_t ws_size,
                              hipStream_t stream) {
  const float* pred = (const float*)d_in[0];
  const float* cxyz = (const float*)d_in[1];
  const float* crgb = (const float*)d_in[2];
  const float* txyz = (const float*)d_in[3];
  const float* trgb = (const float*)d_in[4];
  const int*   ktgt = (const int*)d_in[5];
  const int*   pnum = (const int*)d_in[6];
  int L = in_sizes[0];
  int N = in_sizes[3] / 3;

  // workspace layout: 16B arrays first, then 8B, 4B, bytes
  char* ws = (char*)d_ws;
  size_t off = 0;
  float4* klist  = (float4*)(ws + off);   off += (size_t)L * 16;
  float4* ttile  = (float4*)(ws + off);   off += (size_t)((N + 3) & ~3) * 16;
  float4* numden = (float4*)(ws + off);   off += (size_t)L * 16;
  float4* zcolor = (float4*)(ws + off);   off += (size_t)L * 16;
  unsigned int* key = (unsigned int*)(ws + off); off += (size_t)L * 4;  // uint4-aligned
  ull* tmin      = (ull*)(ws + off);      off += (size_t)((N + 1) & ~1) * 8;
  int* keep      = (int*)(ws + off);      off += (size_t)L * 4;
  int* kidx      = (int*)(ws + off);      off += (size_t)L * 4;
  int* zerohit   = (int*)(ws + off);      off += (size_t)L * 4;
  int* fidx      = (int*)(ws + off);      off += (size_t)L * 4;
  float* thr_slot = (float*)(ws + off);   off += 16;
  int* counters  = (int*)(ws + off);      off += 256;   // [0]=kcount
  unsigned char* islm = (unsigned char*)(ws + off); off += ((size_t)L + 15) & ~15ull;
  float* out = (float*)d_out;

  int nbL = (L + 255) / 256;     // 64
  int nbN = (N + 255) / 256;     // 40
  int NBW = (N + 31) / 32;       // 313 backward blocks (32 queries each)
  int NFW = (L + 31) / 32;       // 512 forward blocks max (early-exit at kc)
  int mx = max(L, N);

  k_prep<<<(mx + 255) / 256, 256, 0, stream>>>(
      pred, txyz, ttile, numden, zerohit, key, islm, counters, out, L, N);

  k_sel<<<1, 256, 0, stream>>>(key, pnum, thr_slot, L);

  k_keepc<<<nbL, 256, 0, stream>>>(
      pred, islm, thr_slot, cxyz, ktgt, keep, klist, kidx, counters, out, L);

  k_scanw<<<NBW + NFW, 256, 0, stream>>>(
      txyz, klist, kidx, ttile, counters, tmin, fidx, L, N, NBW);

  k_scatter<<<nbN, 256, 0, stream>>>(trgb, tmin, numden, zerohit, zcolor, N);

  k_loss<<<nbL, 256, 0, stream>>>(
      crgb, trgb, keep, numden, zerohit, zcolor, fidx, out, L);
}